// Round 8
// baseline (505.748 us; speedup 1.0000x reference)
//
#include <hip/hip_runtime.h>

typedef __attribute__((ext_vector_type(8))) short short8;
typedef __attribute__((ext_vector_type(4))) float f32x4;

#define DIM 1024
#define NH 16
#define HD 64
#define LAT 128
#define QR 256
#define NCAT (LAT + QR) /* 384 */
#define BB 4
#define SS 2048
#define BS (BB * SS) /* 8192 */

// exp(s*0.125) == exp2(s * 0.125*log2(e))
#define SCALE_LOG2E 0.18033688011112042f

__device__ __forceinline__ unsigned short f2b(float f) {
  unsigned int u = __builtin_bit_cast(unsigned int, f);
  u += 0x7FFFu + ((u >> 16) & 1u); // RNE
  return (unsigned short)(u >> 16);
}
__device__ __forceinline__ float b2f(unsigned short h) {
  unsigned int u = ((unsigned int)h) << 16;
  return __builtin_bit_cast(float, u);
}
// pack hi16(f0)|hi16(f1)<<16 with round-half-up (safe: inputs >= 0, no NaN)
__device__ __forceinline__ unsigned int pack_bf16_pair(float f0, float f1) {
  unsigned int u0 = __builtin_bit_cast(unsigned int, f0) + 0x8000u;
  unsigned int u1 = __builtin_bit_cast(unsigned int, f1) + 0x8000u;
  return __builtin_amdgcn_perm(u1, u0, 0x07060302u);
}

__global__ __launch_bounds__(256) void cvt_x(const float* __restrict__ in,
                                             unsigned short* __restrict__ out, int n4) {
  int i = blockIdx.x * 256 + threadIdx.x;
  if (i >= n4) return;
  f32x4 v = ((const f32x4*)in)[i];
  ushort4 o;
  o.x = f2b(v[0]); o.y = f2b(v[1]); o.z = f2b(v[2]); o.w = f2b(v[3]);
  ((ushort4*)out)[i] = o;
}

// Fused prep: all 5 weight transposes (f32 [K][N] -> bf16 [N][K], 64x64 LDS
// tiles) + bias concat, one launch.
__global__ __launch_bounds__(256) void prep_weights(
    const float* __restrict__ w_kvc, const float* __restrict__ w_qc,
    const float* __restrict__ w_kvu, const float* __restrict__ w_qu,
    const float* __restrict__ w_o, const float* __restrict__ b_kvc,
    const float* __restrict__ b_qc, unsigned short* __restrict__ wcatT,
    unsigned short* __restrict__ wkvuT, unsigned short* __restrict__ wquT,
    unsigned short* __restrict__ woT, float* __restrict__ bias_cat) {
  __shared__ unsigned short T[64 * 72];
  const int id = blockIdx.x;
  const int tid = threadIdx.x;
  if (id >= 480) { // bias concat (384 floats)
    if (tid < LAT) bias_cat[tid] = b_kvc[tid];
    else bias_cat[tid] = b_qc[tid - LAT];
    if (tid < 128) bias_cat[tid + 256] = b_qc[tid + 128];
    return;
  }
  const float* in; unsigned short* out; int K, N, tile;
  if (id < 32)       { in = w_kvc; out = wcatT;                       K = DIM; N = LAT;     tile = id; }
  else if (id < 96)  { in = w_qc;  out = wcatT + (size_t)LAT * DIM;   K = DIM; N = QR;      tile = id - 32; }
  else if (id < 160) { in = w_kvu; out = wkvuT;                       K = LAT; N = 2 * DIM; tile = id - 96; }
  else if (id < 224) { in = w_qu;  out = wquT;                        K = QR;  N = DIM;     tile = id - 160; }
  else               { in = w_o;   out = woT;                         K = DIM; N = DIM;     tile = id - 224; }
  const int ktiles = K >> 6;
  const int k0 = (tile % ktiles) * 64, n0 = (tile / ktiles) * 64;
  {
    const int r = tid >> 2, cq = (tid & 3) * 16;
#pragma unroll
    for (int j = 0; j < 4; ++j) {
      f32x4 v = *(const f32x4*)(in + (size_t)(k0 + r) * N + n0 + cq + j * 4);
      ushort4 o;
      o.x = f2b(v[0]); o.y = f2b(v[1]); o.z = f2b(v[2]); o.w = f2b(v[3]);
      *(ushort4*)(T + r * 72 + cq + j * 4) = o;
    }
  }
  __syncthreads();
#pragma unroll
  for (int s = 0; s < 2; ++s) {
    int idx = tid + s * 256;
    int nr = idx >> 3, kg = (idx & 7) * 8;
    short8 o;
#pragma unroll
    for (int i = 0; i < 8; i++) o[i] = T[(kg + i) * 72 + nr];
    *(short8*)(out + (size_t)(n0 + nr) * K + k0 + kg) = o;
  }
}

// V (cols DIM..2*DIM of kvup) -> VT[b][d][s]  (bf16)
__global__ __launch_bounds__(256) void transpose_v(const unsigned short* __restrict__ KVb,
                                                   unsigned short* __restrict__ VTb) {
  __shared__ unsigned short T[64 * 72];
  const int tid = threadIdx.x;
  const int st = blockIdx.x, dt = blockIdx.y, b = blockIdx.z;
  const int s0 = st * 64, d0 = dt * 64;
#pragma unroll
  for (int t = 0; t < 2; ++t) {
    int idx = tid + t * 256;
    int r = idx >> 3, c = idx & 7;
    short8 v = *(const short8*)(KVb + (size_t)(b * SS + s0 + r) * (2 * DIM) + DIM + d0 + c * 8);
    *(short8*)(T + r * 72 + c * 8) = v;
  }
  __syncthreads();
#pragma unroll
  for (int t = 0; t < 2; ++t) {
    int idx = tid + t * 256;
    int dr = idx >> 3, cg = idx & 7;
    short8 o;
#pragma unroll
    for (int i = 0; i < 8; i++) o[i] = T[(cg * 8 + i) * 72 + dr];
    *(short8*)(VTb + (size_t)(b * DIM + d0 + dr) * SS + s0 + cg * 8) = o;
  }
}

// C[M,N] = A[M,K](bf16, row stride lda) @ WT[N,K](bf16) + bias; 64x64/wave,
// 128x128/block. K-loop software-pipelined (ping-pong frag sets).
__global__ __launch_bounds__(256) void gemm_bf16(const unsigned short* __restrict__ A,
                                                 const unsigned short* __restrict__ WT,
                                                 const float* __restrict__ bias,
                                                 float* __restrict__ outF,
                                                 unsigned short* __restrict__ outB,
                                                 int N, int K, int lda, int ldout) {
  const int tid = threadIdx.x;
  const int wave = tid >> 6, lane = tid & 63;
  const int ln = lane & 15, quad = lane >> 4;
  const int m0 = blockIdx.x * 128 + (wave >> 1) * 64;
  const int n0 = blockIdx.y * 128 + (wave & 1) * 64;

  f32x4 acc[4][4];
#pragma unroll
  for (int i = 0; i < 4; i++)
#pragma unroll
    for (int j = 0; j < 4; j++) acc[i][j] = (f32x4){0.f, 0.f, 0.f, 0.f};

  const unsigned short* Ap = A + (size_t)(m0 + ln) * lda + quad * 8;
  const unsigned short* Wp = WT + (size_t)(n0 + ln) * K + quad * 8;

  short8 aA[4], bA[4], aB[4], bB[4];
#pragma unroll
  for (int i = 0; i < 4; i++) {
    aA[i] = *(const short8*)(Ap + (size_t)i * 16 * lda);
    bA[i] = *(const short8*)(Wp + (size_t)i * 16 * K);
  }
  for (int k0 = 0; k0 < K; k0 += 64) {
    const bool hasB = (k0 + 32 < K);
    if (hasB) {
#pragma unroll
      for (int i = 0; i < 4; i++) {
        aB[i] = *(const short8*)(Ap + (size_t)i * 16 * lda + k0 + 32);
        bB[i] = *(const short8*)(Wp + (size_t)i * 16 * K + k0 + 32);
      }
    }
#pragma unroll
    for (int mi = 0; mi < 4; mi++)
#pragma unroll
      for (int ni = 0; ni < 4; ni++)
        acc[mi][ni] =
            __builtin_amdgcn_mfma_f32_16x16x32_bf16(aA[mi], bA[ni], acc[mi][ni], 0, 0, 0);
    if (k0 + 64 < K) {
#pragma unroll
      for (int i = 0; i < 4; i++) {
        aA[i] = *(const short8*)(Ap + (size_t)i * 16 * lda + k0 + 64);
        bA[i] = *(const short8*)(Wp + (size_t)i * 16 * K + k0 + 64);
      }
    }
    if (hasB) {
#pragma unroll
      for (int mi = 0; mi < 4; mi++)
#pragma unroll
        for (int ni = 0; ni < 4; ni++)
          acc[mi][ni] =
              __builtin_amdgcn_mfma_f32_16x16x32_bf16(aB[mi], bB[ni], acc[mi][ni], 0, 0, 0);
    }
  }

#pragma unroll
  for (int mi = 0; mi < 4; mi++) {
    const int row = m0 + mi * 16 + quad * 4;
#pragma unroll
    for (int ni = 0; ni < 4; ni++) {
      const int col = n0 + ni * 16 + ln;
      const float bv = bias[col];
#pragma unroll
      for (int r = 0; r < 4; r++) {
        float v = acc[mi][ni][r] + bv;
        size_t o = (size_t)(row + r) * ldout + col;
        if (outF) outF[o] = v;
        if (outB) outB[o] = f2b(v);
      }
    }
  }
}

// Small-N GEMM: 64x64/block, 32x32/wave; K-loop software-pipelined.
__global__ __launch_bounds__(256) void gemm_n64(const unsigned short* __restrict__ A,
                                                const unsigned short* __restrict__ WT,
                                                const float* __restrict__ bias,
                                                unsigned short* __restrict__ outB,
                                                int K, int ldout) {
  const int tid = threadIdx.x;
  const int wave = tid >> 6, lane = tid & 63;
  const int ln = lane & 15, quad = lane >> 4;
  const int m0 = blockIdx.x * 64 + (wave >> 1) * 32;
  const int n0 = blockIdx.y * 64 + (wave & 1) * 32;

  f32x4 acc[2][2];
#pragma unroll
  for (int i = 0; i < 2; i++)
#pragma unroll
    for (int j = 0; j < 2; j++) acc[i][j] = (f32x4){0.f, 0.f, 0.f, 0.f};

  const unsigned short* Ap = A + (size_t)(m0 + ln) * K + quad * 8;
  const unsigned short* Wp = WT + (size_t)(n0 + ln) * K + quad * 8;

  short8 aA[2], bA[2], aB[2], bB[2];
#pragma unroll
  for (int i = 0; i < 2; i++) {
    aA[i] = *(const short8*)(Ap + (size_t)i * 16 * K);
    bA[i] = *(const short8*)(Wp + (size_t)i * 16 * K);
  }
  for (int k0 = 0; k0 < K; k0 += 64) {
    const bool hasB = (k0 + 32 < K);
    if (hasB) {
#pragma unroll
      for (int i = 0; i < 2; i++) {
        aB[i] = *(const short8*)(Ap + (size_t)i * 16 * K + k0 + 32);
        bB[i] = *(const short8*)(Wp + (size_t)i * 16 * K + k0 + 32);
      }
    }
#pragma unroll
    for (int mi = 0; mi < 2; mi++)
#pragma unroll
      for (int ni = 0; ni < 2; ni++)
        acc[mi][ni] =
            __builtin_amdgcn_mfma_f32_16x16x32_bf16(aA[mi], bA[ni], acc[mi][ni], 0, 0, 0);
    if (k0 + 64 < K) {
#pragma unroll
      for (int i = 0; i < 2; i++) {
        aA[i] = *(const short8*)(Ap + (size_t)i * 16 * K + k0 + 64);
        bA[i] = *(const short8*)(Wp + (size_t)i * 16 * K + k0 + 64);
      }
    }
    if (hasB) {
#pragma unroll
      for (int mi = 0; mi < 2; mi++)
#pragma unroll
        for (int ni = 0; ni < 2; ni++)
          acc[mi][ni] =
              __builtin_amdgcn_mfma_f32_16x16x32_bf16(aB[mi], bB[ni], acc[mi][ni], 0, 0, 0);
    }
  }

#pragma unroll
  for (int mi = 0; mi < 2; mi++) {
    const int row = m0 + mi * 16 + quad * 4;
#pragma unroll
    for (int ni = 0; ni < 2; ni++) {
      const int col = n0 + ni * 16 + ln;
      const float bv = bias[col];
#pragma unroll
      for (int r = 0; r < 4; r++)
        outB[(size_t)(row + r) * ldout + col] = f2b(acc[mi][ni][r] + bv);
    }
  }
}

// MFMA flash attention, causal, fixed-max softmax, S^T orientation,
// BARRIER-FREE K-loop: no LDS staging of K/V — each wave loads its MFMA
// fragments directly from global (16 rows x 64B contiguous per frag load;
// L1/L2-resident; the 4 waves of a block walk the same kt sequence so L1
// absorbs the redundancy). P round-trips through per-wave LDS (same-wave
// ordering, no barrier). Only the epilogue has 2 barriers.
// Block = 128 q-rows x (head,batch), 256 threads = 4 waves; wave w owns
// q-rows {s0 + mi*64 + w*16 + [0,16)} for mi in {0,1}.
// ktmax = 2qt+1 for every wave; mi=0 diag at kt=2qt, mi=1 diag at kt=2qt+1.
__global__ __launch_bounds__(256) void attn_mfma(const unsigned short* __restrict__ Qb,
                                                 const unsigned short* __restrict__ KVb,
                                                 const unsigned short* __restrict__ VTb,
                                                 unsigned short* __restrict__ ctxB) {
  __shared__ unsigned short smem[128 * 72]; // P regions; reused for epilogue
  const int tid = threadIdx.x;
  const int wave = tid >> 6, lane = tid & 63;
  const int ln = lane & 15, quad = lane >> 4;
  const int qt = (gridDim.x - 1) - blockIdx.x; // big blocks launch first
  const int h = blockIdx.y, b = blockIdx.z;
  const int s0 = qt * 128;
  const int ktmax = 2 * qt + 1;

  short8 qfrag[2][2]; // B-operand: rows = q
#pragma unroll
  for (int mi = 0; mi < 2; mi++) {
    const unsigned short* qp =
        Qb + (size_t)(b * SS + s0 + mi * 64 + wave * 16 + ln) * DIM + h * HD + quad * 8;
    qfrag[mi][0] = *(const short8*)qp;
    qfrag[mi][1] = *(const short8*)(qp + 32);
  }

  f32x4 octx[2][4]; // PV acc: row q=quad*4+r (wave tile), col d=dt*16+ln
  float lp[2] = {0.f, 0.f};
#pragma unroll
  for (int mi = 0; mi < 2; mi++)
#pragma unroll
    for (int i = 0; i < 4; i++) octx[mi][i] = (f32x4){0.f, 0.f, 0.f, 0.f};

  // per-(wave,mi) P region: rows wave*32 + mi*16 .. +16
  unsigned short* Pw0 = smem + (wave * 32) * 72;
  unsigned short* Pw1 = smem + (wave * 32 + 16) * 72;

  // fragment base pointers
  const unsigned short* Kb = KVb + (size_t)(b * SS + ln) * (2 * DIM) + h * HD + quad * 8;
  const unsigned short* Vb = VTb + (size_t)(b * DIM + h * HD + ln) * SS + quad * 8;

  for (int kt = 0; kt <= ktmax; ++kt) {
    const int k0g = kt * 64;
    const bool act0 = (kt < ktmax);     // mi=0 ends one tile earlier
    const bool diag0 = (kt == ktmax - 1);
    const bool diag1 = (kt == ktmax);

    // ---- K fragments (A-operand: m=key=k0g+nt*16+ln, k=d=kc*32+quad*8+j)
    short8 kfrag[2][4];
#pragma unroll
    for (int kc = 0; kc < 2; kc++)
#pragma unroll
      for (int nt = 0; nt < 4; nt++) {
        if (diag1 && nt > wave) continue; // strip fully masked for this wave
        kfrag[kc][nt] =
            *(const short8*)(Kb + (size_t)(k0g + nt * 16) * (2 * DIM) + kc * 32);
      }
    // ---- V fragments (B-operand: n=d=dt*16+ln, k=key=k0g+kc*32+quad*8+j)
    short8 vfrag[2][4];
#pragma unroll
    for (int kc = 0; kc < 2; kc++) {
      if (diag1 && kc == 1 && wave < 2) continue;
#pragma unroll
      for (int dt = 0; dt < 4; dt++)
        vfrag[kc][dt] = *(const short8*)(Vb + (size_t)(dt * 16) * SS + k0g + kc * 32);
    }

    // ---- QK^T (S^T orientation)
    f32x4 sacc[2][4];
#pragma unroll
    for (int mi = 0; mi < 2; mi++)
#pragma unroll
      for (int nt = 0; nt < 4; nt++) sacc[mi][nt] = (f32x4){0.f, 0.f, 0.f, 0.f};
#pragma unroll
    for (int kc = 0; kc < 2; kc++)
#pragma unroll
      for (int nt = 0; nt < 4; nt++) {
        if (diag1 && nt > wave) continue;
        if (act0 && !(diag0 && nt > wave))
          sacc[0][nt] = __builtin_amdgcn_mfma_f32_16x16x32_bf16(kfrag[kc][nt],
                                                                qfrag[0][kc], sacc[0][nt],
                                                                0, 0, 0);
        sacc[1][nt] = __builtin_amdgcn_mfma_f32_16x16x32_bf16(kfrag[kc][nt],
                                                              qfrag[1][kc], sacc[1][nt],
                                                              0, 0, 0);
      }

    // ---- fixed-max softmax + packed P writes (per-wave LDS, no barrier)
#pragma unroll
    for (int mi = 0; mi < 2; mi++) {
      if (mi == 0 && !act0) continue;
      const bool dg = mi ? diag1 : diag0;
      unsigned short* Pw = mi ? Pw1 : Pw0;
      const int qg = wave * 16 + ln; // q relative to this wave's mi-tile
      float lacc = 0.f;
      if (dg) {
#pragma unroll
        for (int nt = 0; nt < 4; nt++) {
          float pe[4];
#pragma unroll
          for (int r = 0; r < 4; r++) {
            float p = __builtin_exp2f(sacc[mi][nt][r] * SCALE_LOG2E);
            if ((nt * 16 + quad * 4 + r) > qg) p = 0.f; // key beyond q
            lacc += p;
            pe[r] = p;
          }
          uint2 pw;
          pw.x = pack_bf16_pair(pe[0], pe[1]);
          pw.y = pack_bf16_pair(pe[2], pe[3]);
          *(uint2*)(Pw + ln * 72 + nt * 16 + quad * 4) = pw;
        }
      } else {
#pragma unroll
        for (int nt = 0; nt < 4; nt++) {
          float pe[4];
#pragma unroll
          for (int r = 0; r < 4; r++) {
            float p = __builtin_exp2f(sacc[mi][nt][r] * SCALE_LOG2E);
            lacc += p;
            pe[r] = p;
          }
          uint2 pw;
          pw.x = pack_bf16_pair(pe[0], pe[1]);
          pw.y = pack_bf16_pair(pe[2], pe[3]);
          *(uint2*)(Pw + ln * 72 + nt * 16 + quad * 4) = pw;
        }
      }
      lp[mi] += lacc;
    }

    // ---- PV
#pragma unroll
    for (int kc = 0; kc < 2; kc++) {
      const bool skip1 = (diag1 && kc == 1 && wave < 2);
#pragma unroll
      for (int mi = 0; mi < 2; mi++) {
        if (mi == 0 && (!act0 || (diag0 && kc == 1 && wave < 2))) continue;
        if (mi == 1 && skip1) continue;
        unsigned short* Pw = mi ? Pw1 : Pw0;
        short8 pfrag = *(const short8*)(Pw + ln * 72 + kc * 32 + quad * 8);
#pragma unroll
        for (int dt = 0; dt < 4; dt++)
          octx[mi][dt] = __builtin_amdgcn_mfma_f32_16x16x32_bf16(pfrag, vfrag[kc][dt],
                                                                 octx[mi][dt], 0, 0, 0);
      }
    }
  }

  // Denominators: reduce across the 4 quads, broadcast to owned rows.
  float linv[2][4];
#pragma unroll
  for (int mi = 0; mi < 2; mi++) {
    lp[mi] += __shfl_xor(lp[mi], 16, 64);
    lp[mi] += __shfl_xor(lp[mi], 32, 64);
#pragma unroll
    for (int r = 0; r < 4; r++) linv[mi][r] = 1.f / __shfl(lp[mi], quad * 4 + r, 64);
  }

  // Epilogue: normalize, stage 128x64 tile through smem, coalesced 16B stores.
  __syncthreads();
#pragma unroll
  for (int mi = 0; mi < 2; mi++)
#pragma unroll
    for (int r = 0; r < 4; r++) {
#pragma unroll
      for (int dt = 0; dt < 4; dt++)
        smem[(mi * 64 + wave * 16 + quad * 4 + r) * 72 + dt * 16 + ln] =
            f2b(octx[mi][dt][r] * linv[mi][r]);
    }
  __syncthreads();
#pragma unroll
  for (int t = 0; t < 4; ++t) {
    int idx = tid + t * 256;
    int row = idx >> 3, c = idx & 7;
    short8 v = *(const short8*)(smem + row * 72 + c * 8);
    *(short8*)(ctxB + (size_t)(b * SS + s0 + row) * DIM + h * HD + c * 8) = v;
  }
}

extern "C" void kernel_launch(void* const* d_in, const int* in_sizes, int n_in,
                              void* d_out, int out_size, void* d_ws, size_t ws_size,
                              hipStream_t stream) {
  const float* x     = (const float*)d_in[0];
  const float* w_kvc = (const float*)d_in[2];
  const float* b_kvc = (const float*)d_in[3];
  const float* w_kvu = (const float*)d_in[4];
  const float* b_kvu = (const float*)d_in[5];
  const float* w_qc  = (const float*)d_in[6];
  const float* b_qc  = (const float*)d_in[7];
  const float* w_qu  = (const float*)d_in[8];
  const float* b_qu  = (const float*)d_in[9];
  const float* w_o   = (const float*)d_in[10];
  const float* b_o   = (const float*)d_in[11];
  float* out = (float*)d_out;

  unsigned short* xb     = (unsigned short*)d_ws;          // [BS][DIM]; reused as VT
  unsigned short* wcatT  = xb + (size_t)BS * DIM;          // [NCAT][DIM]
  unsigned short* wkvuT  = wcatT + (size_t)NCAT * DIM;     // [2*DIM][LAT]
  unsigned short* wquT   = wkvuT + (size_t)LAT * 2 * DIM;  // [DIM][QR]
  unsigned short* woT    = wquT + (size_t)QR * DIM;        // [DIM][DIM]
  unsigned short* kvqlat = woT + (size_t)DIM * DIM;        // [BS][NCAT] (kv | q)
  unsigned short* kvup   = kvqlat + (size_t)BS * NCAT;     // [BS][2*DIM] (K | V)
  unsigned short* Qbuf   = kvup + (size_t)BS * 2 * DIM;    // [BS][DIM]
  unsigned short* ctx    = Qbuf + (size_t)BS * DIM;        // [BS][DIM]
  float* bias_cat        = (float*)(ctx + (size_t)BS * DIM); // [NCAT]

  cvt_x<<<(BS * DIM / 4 + 255) / 256, 256, 0, stream>>>(x, xb, BS * DIM / 4);
  prep_weights<<<481, 256, 0, stream>>>(w_kvc, w_qc, w_kvu, w_qu, w_o, b_kvc, b_qc,
                                        wcatT, wkvuT, wquT, woT, bias_cat);

  // fused stage-1: [kvlat | qlat] = x @ [w_kvc | w_qc]
  gemm_n64<<<dim3(BS / 64, NCAT / 64), 256, 0, stream>>>(xb, wcatT, bias_cat, kvqlat,
                                                         DIM, NCAT);
  // stage-2
  gemm_bf16<<<dim3(BS / 128, 2 * DIM / 128), 256, 0, stream>>>(
      kvqlat, wkvuT, b_kvu, nullptr, kvup, 2 * DIM, LAT, NCAT, 2 * DIM);
  unsigned short* VT = xb; // xb dead after stage-1
  transpose_v<<<dim3(SS / 64, DIM / 64, BB), 256, 0, stream>>>(kvup, VT);
  gemm_bf16<<<dim3(BS / 128, DIM / 128), 256, 0, stream>>>(
      kvqlat + LAT, wquT, b_qu, nullptr, Qbuf, DIM, QR, NCAT, DIM);
  attn_mfma<<<dim3(SS / 128, NH, BB), 256, 0, stream>>>(Qbuf, kvup, VT, ctx);
  gemm_bf16<<<dim3(BS / 128, DIM / 128), 256, 0, stream>>>(ctx, woT, b_o, out, nullptr,
                                                           DIM, DIM, DIM, DIM);
}